// Round 3
// baseline (249.433 us; speedup 1.0000x reference)
//
#include <hip/hip_runtime.h>
#include <hip/hip_bf16.h>

#define D_ 128
#define E_ 100
#define K_ 4
#define C_ 400
#define CH 64   // atom chunks in k_sums

// Kernel 1: per-atom argmin over its element's 4 codes, write h_q (f32),
// code as f32 into the atom_types slot, accumulate commitment loss.
// 16 lanes per atom, 8 contiguous floats per lane.
__global__ __launch_bounds__(256) void k_assign(
    const float* __restrict__ h, const int* __restrict__ ei,
    const float* __restrict__ cb, float* __restrict__ hq,
    float* __restrict__ codes, float* __restrict__ loss_acc, int N) {
  const int lane16 = threadIdx.x & 15;
  const int gid0 = (blockIdx.x * blockDim.x + threadIdx.x) >> 4;
  const int ngroups = (gridDim.x * blockDim.x) >> 4;
  float loss = 0.f;
  for (int a = gid0; a < N; a += ngroups) {
    const float* hrow = h + (size_t)a * D_ + lane16 * 8;
    float4 h0 = reinterpret_cast<const float4*>(hrow)[0];
    float4 h1 = reinterpret_cast<const float4*>(hrow)[1];
    int e = ei[a];
    const float* cbase = cb + (size_t)e * (K_ * D_);
    float p[4];
#pragma unroll
    for (int j = 0; j < 4; ++j) {
      const float* cr = cbase + j * D_ + lane16 * 8;
      float4 c0 = reinterpret_cast<const float4*>(cr)[0];
      float4 c1 = reinterpret_cast<const float4*>(cr)[1];
      float d0 = h0.x - c0.x, d1 = h0.y - c0.y;
      float d2 = h0.z - c0.z, d3 = h0.w - c0.w;
      float d4 = h1.x - c1.x, d5 = h1.y - c1.y;
      float d6 = h1.z - c1.z, d7 = h1.w - c1.w;
      p[j] = ((d0*d0 + d1*d1) + (d2*d2 + d3*d3)) +
             ((d4*d4 + d5*d5) + (d6*d6 + d7*d7));
    }
    // reduce across the 16-lane group (xor 1,2,4,8) — all lanes end identical
#pragma unroll
    for (int s = 1; s < 16; s <<= 1) {
#pragma unroll
      for (int j = 0; j < 4; ++j) p[j] += __shfl_xor(p[j], s, 64);
    }
    float bp = p[0]; int best = 0;
    if (p[1] < bp) { bp = p[1]; best = 1; }
    if (p[2] < bp) { bp = p[2]; best = 2; }
    if (p[3] < bp) { bp = p[3]; best = 3; }
    // reload winning codebook row (L1/L2 hit) and emit f32 h_q = z_q
    const float* br = cbase + best * D_ + lane16 * 8;
    float4 b0 = reinterpret_cast<const float4*>(br)[0];
    float4 b1 = reinterpret_cast<const float4*>(br)[1];
    float* orow = hq + (size_t)a * D_ + lane16 * 8;
    reinterpret_cast<float4*>(orow)[0] = b0;
    reinterpret_cast<float4*>(orow)[1] = b1;
    if (lane16 == 0) {
      codes[a] = (float)(e * K_ + best);
      loss += bp;   // sum_d (h-c_best)^2
    }
  }
  __shared__ float bl;
  if (threadIdx.x == 0) bl = 0.f;
  __syncthreads();
  if (lane16 == 0) atomicAdd(&bl, loss);
  __syncthreads();
  if (threadIdx.x == 0) atomicAdd(loss_acc, bl);
}

// Kernel 2: segment sums + counts. Grid = CH chunks x 4 column-slices.
// Each block accumulates [400][32] f32 in LDS, then flushes with atomics.
__global__ __launch_bounds__(1024) void k_sums(
    const float* __restrict__ h, const float* __restrict__ codes,
    float* __restrict__ sums, float* __restrict__ counts, int N) {
  const int slice = blockIdx.x & 3;
  const int chunk = blockIdx.x >> 2;
  __shared__ float acc[C_ * 32];
  __shared__ float cnt[C_];
  for (int i = threadIdx.x; i < C_ * 32; i += 1024) acc[i] = 0.f;
  if (slice == 0)
    for (int i = threadIdx.x; i < C_; i += 1024) cnt[i] = 0.f;
  __syncthreads();
  const int apc = N / CH;                  // atoms per chunk
  const int a0 = chunk * apc;
  const int sub = threadIdx.x >> 5;        // 0..31 atoms per iter
  const int col = threadIdx.x & 31;
  for (int it = 0; it < apc / 32; ++it) {
    int a = a0 + it * 32 + sub;
    int code = (int)codes[a];
    float v = h[(size_t)a * D_ + slice * 32 + col];
    atomicAdd(&acc[code * 32 + col], v);
    if (slice == 0 && col == 0) atomicAdd(&cnt[code], 1.0f);
  }
  __syncthreads();
  for (int i = threadIdx.x; i < C_ * 32; i += 1024)
    atomicAdd(&sums[(size_t)(i >> 5) * D_ + slice * 32 + (i & 31)], acc[i]);
  if (slice == 0)
    for (int i = threadIdx.x; i < C_; i += 1024) atomicAdd(&counts[i], cnt[i]);
}

// Kernel 3: EMA finalize + loss scalar (all f32 outputs).
__global__ __launch_bounds__(256) void k_final(
    const float* __restrict__ cb, const float* __restrict__ ecnt,
    const float* __restrict__ esum, const float* __restrict__ ws,
    float* __restrict__ out, int N) {
  const float* sums = ws;
  const float* counts = ws + C_ * D_;
  int idx = blockIdx.x * 256 + threadIdx.x;
  const size_t base = (size_t)N * D_ + N + 1;   // start of new_codebook
  if (idx < C_ * D_) {
    int c = idx >> 7;
    int e4 = (c >> 2) << 2;
    bool present = (counts[e4] + counts[e4 + 1] + counts[e4 + 2] + counts[e4 + 3]) > 0.f;
    float es = esum[idx];
    float s  = sums[idx];
    float ns = present ? 0.99f * es + 0.01f * s : es;
    float ec = ecnt[c];
    float nc = present ? 0.99f * ec + 0.01f * counts[c] : ec;
    float ncbv = present ? ns / fmaxf(nc, 1e-5f) : cb[idx];
    out[base + idx] = ncbv;                           // new_codebook
    if ((idx & 127) == 0) out[base + C_ * D_ + c] = nc;   // new_count
    out[base + C_ * D_ + C_ + idx] = ns;              // new_sum
  }
  if (idx == 0) {
    float loss = ws[C_ * D_ + C_];
    out[(size_t)N * D_ + N] = 0.25f * loss / ((float)N * (float)D_);
  }
}

extern "C" void kernel_launch(void* const* d_in, const int* in_sizes, int n_in,
                              void* d_out, int out_size, void* d_ws, size_t ws_size,
                              hipStream_t stream) {
  // Identify inputs BY SIZE (robust; matches dict order too):
  //   h: N*D (largest), elem_indices: N, codebook: C*D (first of the two),
  //   ema_count: C, ema_embed_sum: C*D (second of the two).
  const float* h = nullptr; const int* ei = nullptr;
  const float* cb = nullptr; const float* ecnt = nullptr; const float* esum = nullptr;
  long hsz = -1; int hidx = -1;
  for (int i = 0; i < n_in; ++i)
    if ((long)in_sizes[i] > hsz) { hsz = in_sizes[i]; hidx = i; }
  h = (const float*)d_in[hidx];
  const int N = (int)(hsz / D_);   // 262144
  for (int i = 0; i < n_in; ++i) {
    if (i == hidx) continue;
    const int s = in_sizes[i];
    if (s == N) ei = (const int*)d_in[i];
    else if (s == C_) ecnt = (const float*)d_in[i];
    else if (s == C_ * D_) { if (!cb) cb = (const float*)d_in[i]; else esum = (const float*)d_in[i]; }
  }

  float* out = (float*)d_out;                 // f32 output buffer
  float* hq  = out;                           // [N*D] h_q (= z_q)
  float* at  = out + (size_t)N * D_;          // [N] atom_types as f32

  float* ws = (float*)d_ws;
  float* sums   = ws;                // [C*D]
  float* counts = ws + C_ * D_;      // [C]
  float* lossp  = ws + C_ * D_ + C_; // [1]

  hipMemsetAsync(d_ws, 0, (size_t)(C_ * D_ + C_ + 1) * sizeof(float), stream);

  k_assign<<<2048, 256, 0, stream>>>(h, ei, cb, hq, at, lossp, N);
  k_sums<<<CH * 4, 1024, 0, stream>>>(h, at, sums, counts, N);
  k_final<<<(C_ * D_ + 255) / 256, 256, 0, stream>>>(cb, ecnt, esum, ws, out, N);
}